// Round 2
// baseline (11078.341 us; speedup 1.0000x reference)
//
#include <hip/hip_runtime.h>
#include <stdint.h>

// LSTM encoder: B=64, S=512, V=32000, E=512, H=1024. Returns final (h, c) fp32.
//
// Round-11: hardened clock-paced lockstep (r10 failed to bench; no counters).
// r9 counters (MfmaUtil 6.9%, VALUBusy 21%, HBM 2.9%) showed >90% of each
// 4.8us step was serialized MALL round trips in the flag protocol. r10
// replaced flags with absolute deadlines from s_memrealtime. r11 keeps that
// but hardens every suspect:
//  - REVERT producer path to r9-proven 8B u64 agent stores (LDS transpose,
//    lane<16 funnel). r10's 16-bit __hip_atomic_store was the one novel
//    codegen path and is gone.
//  - Bounded epoch spin (2ms cap) with local-clock fallback: pacing never
//    depends on a shared value becoming visible. No unbounded spin remains
//    except data recovery, whose producers are guaranteed (co-resident,
//    fire-and-forget).
//  - CROSS-RUN STALENESS FIX (latent in r9, fatal under pure clock pacing):
//    LSB-odd validity can't distinguish this run's h from last run's.
//    init_kernel now clears EVERY A[t] h-region to even/invalid zeros each
//    run (+64MB streaming stores ~= +12us). Ground truth is always
//    this-run data; clock is purely a pacing hint. Kernel-boundary
//    release/acquire makes init's clears visible to lstm; within-run stale
//    L2 lines self-identify as even -> sc1 MALL recovery (r9-proven).
//  - s_sleep(1) in pacing spins (power/fabric-gentle; 26ns granularity).
// Correctness is clock-INDEPENDENT: wrong REFCLK rate or late blocks only
// degrade toward self-timed recovery pacing (slower, still correct).
// Tuning knob: T_TICKS (REFCLK ticks/step, 100MHz). 140 = 1.4us/step.

#define Bsz 64
#define Ssz 512
#define Esz 512
#define Hsz 1024
#define G4  4096
#define Ksz 1536
#define KC  48      // Ksz/32
#define NBLK 256
#define AUNITS 12288            // 16B units per A buffer (KC*256)

#define T_TICKS      140ull     // 1.4 us per step @ 100 MHz REFCLK
#define EPOCH_MARGIN 3000ull    // 30 us: dispatch ramp + Wl staging
#define EPOCH_SPIN_CAP 200000ull // 2 ms: epoch pickup bound

typedef float f32x4 __attribute__((ext_vector_type(4)));
typedef short bf16x8 __attribute__((ext_vector_type(8)));
typedef unsigned long long u64;

// A unit(row,kc,q) = kc*256 + (row>>4)*64 + q*16 + (row&15)
// Wf unit(blk,kc,q,r) = (blk*48+kc)*64 + q*16 + r, r = gate*4+j  (n-col)

__device__ __forceinline__ unsigned short f2bf(float f) {
  union { float f; uint32_t u; } v; v.f = f;
  return (unsigned short)((v.u + 0x7FFFu + ((v.u >> 16) & 1u)) >> 16);  // RNE
}
// nearest ODD-LSB bf16 (validity bit). trunc|1 IS the nearest odd value.
__device__ __forceinline__ unsigned short f2bf_odd(float f) {
  union { float f; uint32_t u; } v; v.f = f;
  return (unsigned short)((v.u >> 16) | 1u);
}
__device__ __forceinline__ float fsig(float x) {
  return __builtin_amdgcn_rcpf(1.0f + __expf(-x));
}
__device__ __forceinline__ float ftanh(float x) {
  return 2.0f * fsig(2.0f * x) - 1.0f;
}

__global__ __launch_bounds__(1024) void wf_kernel(
    const float* __restrict__ Wih, const float* __restrict__ Whh,
    unsigned short* __restrict__ Wf)
{
  __shared__ float tile[32][33];
  const int j0 = blockIdx.x * 32;           // gate-col tile
  const int k0 = blockIdx.y * 32;           // k tile
  const int tx = threadIdx.x & 31, ty = threadIdx.x >> 5;
  const int k = k0 + ty;
  tile[ty][tx] = (k < Hsz) ? Whh[(size_t)k * G4 + (j0 + tx)]
                           : Wih[(size_t)(k - Hsz) * G4 + (j0 + tx)];
  __syncthreads();
  if (threadIdx.x < 128) {
    const int gl = threadIdx.x & 31;        // local gate col in tile
    const int q8 = threadIdx.x >> 5;        // k-octet within kc
    const int g  = j0 + gl;                 // global gate col
    const int blk  = (g & 1023) >> 2;
    const int gate = g >> 10;
    const int r    = gate * 4 + (g & 3);    // n-col within block tile
    const int kc   = k0 >> 5;
    unsigned short pack[8];
    #pragma unroll
    for (int jj = 0; jj < 8; ++jj) pack[jj] = f2bf(tile[q8 * 8 + jj][gl]);
    const size_t unit = (size_t)((blk * KC + kc) * 64 + q8 * 16 + r);
    *(bf16x8*)(Wf + unit * 8) = *(bf16x8*)pack;
  }
}

// Per A[t]: clear h region to even/invalid (t=0: odd-LSB "zero" h) and
// write the emb region. Clearing every run kills cross-run stale-valid data.
__global__ __launch_bounds__(256) void init_kernel(
    const int* __restrict__ seq, const float* __restrict__ emb,
    unsigned short* __restrict__ Abufs, int* __restrict__ bar)
{
  const int t = blockIdx.x, tid = threadIdx.x;
  unsigned short* At = Abufs + (size_t)t * AUNITS * 8;
  {  // h region = units [0, 8192) = kc 0..31
    uint4 z;
    const uint32_t zv = (t == 0) ? 0x00010001u : 0u;
    z.x = z.y = z.z = z.w = zv;
    for (int i = tid; i < 8192; i += 256) ((uint4*)At)[i] = z;
  }
  const int c = 2 * tid;                    // emb col pair
  const int kc = 32 + (c >> 5), q = (c >> 3) & 3, j = c & 7;
  for (int row = 0; row < Bsz; ++row) {
    const int token = seq[row * Ssz + t];
    float2 e = ((const float2*)(emb + (size_t)token * Esz))[tid];
    uint32_t pe = (uint32_t)f2bf(e.x) | ((uint32_t)f2bf(e.y) << 16);
    const size_t unit = (size_t)(kc * 256 + (row >> 4) * 64 + q * 16 + (row & 15));
    *(uint32_t*)(At + unit * 8 + j) = pe;
  }
  if (t == 0) {
    for (int i = tid; i < 1024; i += 256) bar[i] = 0;
  }
}

__global__ __launch_bounds__(256, 1) void lstm_kernel(
    const float* __restrict__ bias, const unsigned short* __restrict__ Wf,
    unsigned short* __restrict__ Abufs,
    int* __restrict__ bar, float* __restrict__ out)
{
  const int blk  = blockIdx.x;          // owns h-cols [blk*4, blk*4+4)
  const int tid  = threadIdx.x;
  const int lane = tid & 63;
  const int w    = tid >> 6;            // wave = M-tile rows [w*16, w*16+16)
  const int l15  = lane & 15, quad = lane >> 4;

  __shared__ uint4 Wl[KC * 64];                 // 48 KB, resident all steps
  __shared__ unsigned short Hs[4][16][4];       // 512 B per-wave h transpose

  // publish epoch ASAP so the margin covers everyone's staging
  u64* epoch_p = (u64*)bar;
  if (blk == 0 && tid == 0) {
    __hip_atomic_store(epoch_p,
                       __builtin_amdgcn_s_memrealtime() + EPOCH_MARGIN,
                       __ATOMIC_RELAXED, __HIP_MEMORY_SCOPE_AGENT);
  }

  {  // one-time: W slice -> LDS
    const uint4* wfb = (const uint4*)Wf + (size_t)blk * (KC * 64);
    for (int i = tid; i < KC * 64; i += 256) Wl[i] = wfb[i];
  }

  // cell ownership: lanes l15<4 own (rows w*16+quad*4+r, col blk*4+l15)
  const bool owner = (l15 < 4);
  const int  bj = blk * 4 + (l15 & 3);
  const float bi  = bias[bj],        bf_ = bias[Hsz + bj];
  const float bg_ = bias[2*Hsz + bj], bo  = bias[3*Hsz + bj];
  float creg[4] = {0.f, 0.f, 0.f, 0.f};

  // h-store addressing: this block's cols live at (hkc, hq, hj0)
  const int hkc = blk >> 3, hq = (blk >> 1) & 3, hj0 = (blk & 1) * 4;

  __syncthreads();                      // Wl staged (only block barrier)

  // ---- emb prefetch (1 step ahead) ----
  uint4 eA[16];
  {
    const uint4* E0 = (const uint4*)Abufs;
    #pragma unroll
    for (int i = 0; i < 16; ++i) eA[i] = E0[(32 + i) * 256 + w * 64 + lane];
  }

  // ---- one-time epoch pickup: bounded spin, local-clock fallback ----
  u64 epoch = 0;
  {
    const u64 t0 = __builtin_amdgcn_s_memrealtime();
    do {
      epoch = __hip_atomic_load(epoch_p, __ATOMIC_RELAXED, __HIP_MEMORY_SCOPE_AGENT);
      if (epoch != 0) break;
      __builtin_amdgcn_s_sleep(1);
    } while (__builtin_amdgcn_s_memrealtime() - t0 < EPOCH_SPIN_CAP);
    if (epoch == 0) epoch = __builtin_amdgcn_s_memrealtime();  // self-timed
  }
  u64 dl = epoch;

  const u64 M = 0x0001000100010001ull;

  for (int t = 0; t < Ssz; ++t) {
    // ---- emb MFMAs (register-only), in the deadline shadow ----
    f32x4 accE = {0.f, 0.f, 0.f, 0.f};
    #pragma unroll
    for (int i = 0; i < 16; ++i)
      accE = __builtin_amdgcn_mfma_f32_16x16x32_bf16(
          __builtin_bit_cast(bf16x8, eA[i]),
          __builtin_bit_cast(bf16x8, Wl[(32 + i) * 64 + lane]), accE, 0, 0, 0);

    // ---- pacing: wait for this step's absolute deadline (no memory) ----
    while (__builtin_amdgcn_s_memrealtime() < dl) __builtin_amdgcn_s_sleep(1);
    dl += T_TICKS;
    asm volatile("" ::: "memory");      // don't hoist the A-loads above

    // ---- h-GEMM: 32 cached loads (XCD-L2 broadcast), LSB-validate ----
    const uint4* Ac = (const uint4*)(Abufs + (size_t)t * AUNITS * 8);
    uint4 abuf[32];
    #pragma unroll
    for (int kc = 0; kc < 32; ++kc) abuf[kc] = Ac[kc * 256 + w * 64 + lane];

    f32x4 acc0 = {0.f, 0.f, 0.f, 0.f};
    f32x4 acc1 = {0.f, 0.f, 0.f, 0.f};
    f32x4 acc2 = {0.f, 0.f, 0.f, 0.f};
    f32x4 acc3 = {0.f, 0.f, 0.f, 0.f};
    #pragma unroll
    for (int kc = 0; kc < 32; ++kc) {
      uint4 a = abuf[kc];
      u64 lo = ((u64)a.y << 32) | a.x;
      u64 hi = ((u64)a.w << 32) | a.z;
      if (__builtin_expect(((lo & M) != M) || ((hi & M) != M), 0)) {
        // raced a producer (or stale-cached line): recover MALL-direct
        const u64* base = (const u64*)Ac + (size_t)(kc * 256 + w * 64 + lane) * 2;
        while ((lo & M) != M)
          lo = __hip_atomic_load(base,     __ATOMIC_RELAXED, __HIP_MEMORY_SCOPE_AGENT);
        while ((hi & M) != M)
          hi = __hip_atomic_load(base + 1, __ATOMIC_RELAXED, __HIP_MEMORY_SCOPE_AGENT);
        a.x = (uint32_t)lo; a.y = (uint32_t)(lo >> 32);
        a.z = (uint32_t)hi; a.w = (uint32_t)(hi >> 32);
      }
      const bf16x8 av = __builtin_bit_cast(bf16x8, a);
      const bf16x8 bv = __builtin_bit_cast(bf16x8, Wl[kc * 64 + lane]);
      if      ((kc & 3) == 0) acc0 = __builtin_amdgcn_mfma_f32_16x16x32_bf16(av, bv, acc0, 0, 0, 0);
      else if ((kc & 3) == 1) acc1 = __builtin_amdgcn_mfma_f32_16x16x32_bf16(av, bv, acc1, 0, 0, 0);
      else if ((kc & 3) == 2) acc2 = __builtin_amdgcn_mfma_f32_16x16x32_bf16(av, bv, acc2, 0, 0, 0);
      else                    acc3 = __builtin_amdgcn_mfma_f32_16x16x32_bf16(av, bv, acc3, 0, 0, 0);
    }
    f32x4 acc;
    acc.x = accE.x + (acc0.x + acc1.x) + (acc2.x + acc3.x);
    acc.y = accE.y + (acc0.y + acc1.y) + (acc2.y + acc3.y);
    acc.z = accE.z + (acc0.z + acc1.z) + (acc2.z + acc3.z);
    acc.w = accE.w + (acc0.w + acc1.w) + (acc2.w + acc3.w);

    // ---- in-wave LSTM cell (acc[r]: gate l15>>2, col l15&3, row +quad*4+r)
    float hv[4];
    #pragma unroll
    for (int r = 0; r < 4; ++r) {
      float gf = __shfl_xor(acc[r], 4);
      float gg = __shfl_xor(acc[r], 8);
      float go = __shfl_xor(acc[r], 12);
      float c  = fsig(gf + bf_) * creg[r]
               + fsig(acc[r] + bi) * ftanh(gg + bg_);
      float h  = fsig(go + bo) * ftanh(c);
      if (owner) { creg[r] = c; hv[r] = h; }
    }

    if (t == Ssz - 1) {
      if (owner) {
        #pragma unroll
        for (int r = 0; r < 4; ++r) {
          const int row = w * 16 + quad * 4 + r;
          out[(size_t)row * Hsz + bj] = hv[r];
          out[(size_t)(Bsz * Hsz) + (size_t)row * Hsz + bj] = creg[r];
        }
      }
      return;
    }

    // ---- fire-and-forget: per-wave LDS transpose -> 8B odd-LSB u64 store
    if (owner) {
      #pragma unroll
      for (int r = 0; r < 4; ++r) Hs[w][quad * 4 + r][l15] = f2bf_odd(hv[r]);
    }
    unsigned short* An = Abufs + (size_t)(t + 1) * AUNITS * 8;
    if (lane < 16) {
      u64 hp = *(const u64*)&Hs[w][lane][0];
      const size_t unit = (size_t)(hkc * 256 + w * 64 + hq * 16 + lane);
      __hip_atomic_store((u64*)(An + unit * 8 + hj0), hp,
                         __ATOMIC_RELAXED, __HIP_MEMORY_SCOPE_AGENT);
    }

    // ---- refill emb prefetch for t+1 (init-written, cached) ----
    const uint4* An4 = (const uint4*)An;
    #pragma unroll
    for (int i = 0; i < 16; ++i) eA[i] = An4[(32 + i) * 256 + w * 64 + lane];
  }
}

extern "C" void kernel_launch(void* const* d_in, const int* in_sizes, int n_in,
                              void* d_out, int out_size, void* d_ws, size_t ws_size,
                              hipStream_t stream) {
  (void)in_sizes; (void)n_in; (void)out_size; (void)ws_size;
  const int*   seq  = (const int*)d_in[0];     // [64][512] int32
  const float* emb  = (const float*)d_in[1];   // [32000][512] fp32
  const float* Wih  = (const float*)d_in[2];   // [512][4096] fp32
  const float* Whh  = (const float*)d_in[3];   // [1024][4096] fp32
  const float* bias = (const float*)d_in[4];   // [4096] fp32
  float* out = (float*)d_out;                  // h[64][1024] then c[64][1024]

  unsigned short* Wf    = (unsigned short*)d_ws;              // 12.58 MB
  unsigned short* Abufs = Wf + (size_t)NBLK * KC * 64 * 8;    // 512*192KB
  int* bar = (int*)(Abufs + (size_t)Ssz * AUNITS * 8);        // epoch + pad

  wf_kernel<<<dim3(G4 / 32, Ksz / 32), 1024, 0, stream>>>(Wih, Whh, Wf);
  init_kernel<<<Ssz, 256, 0, stream>>>(seq, emb, Abufs, bar);
  lstm_kernel<<<NBLK, 256, 0, stream>>>(bias, Wf, Abufs, bar, out);
}

// Round 3
// 3652.027 us; speedup vs baseline: 3.0335x; 3.0335x over previous
//
#include <hip/hip_runtime.h>
#include <stdint.h>

// LSTM encoder: B=64, S=512, V=32000, E=512, H=1024. Returns final (h, c) fp32.
//
// Round-12: data-driven sync with BATCHED concurrent validity polling.
// r11 (clock-paced) passed but ran 21.5us/step: one missed deadline flips
// the run permanently into the recovery path (dl += T can never catch up),
// and r11's recovery spun the 32 units SEQUENTIALLY -> 32 serialized MALL
// round trips per wave per step. The absolute clock is structurally fragile
// (REFCLK uncertainty, no re-anchoring) -> removed entirely.
// Protocol (correctness pieces all r11-proven):
//  - LSB-odd validity is ground truth: valid h shorts have LSB=1; init
//    clears every A[t] h-region to even zeros each run (kills cross-run
//    stale-valid data). Producers fire-and-forget 8B agent stores.
//  - Consumer per step: ONE cached sweep of all 32 units (concurrent,
//    virgin lines; XCD-L2 dedups across blocks), build per-lane 32-bit
//    bad-mask from LSBs; while __any(bad): s_sleep(8) then a guarded
//    ISSUE-pass (agent-scope MALL-direct reloads of only the bad units)
//    split from the CHECK-pass by sched_barrier(0) -> each retry sweep
//    costs ~1 round trip total, not bad-count round trips.
//  - Stale L2/L1 lines (fetched before a producer's store landed) always
//    fail validation and are re-read agent-scope; the cached copy of a
//    given A[t] line is never trusted twice.
//  - No flags, no in-loop barriers, no clock: cadence self-times at
//    store-flight + ~1 poll RT + compute. Early blocks sleep-poll (bounded
//    traffic); late blocks see valid data instantly and catch up.
//  - emb MFMAs + eA prefetch run in the shadow between h-store and sweep.
//  - h-MFMA accumulation split into 4 chains.

#define Bsz 64
#define Ssz 512
#define Esz 512
#define Hsz 1024
#define G4  4096
#define Ksz 1536
#define KC  48      // Ksz/32
#define NBLK 256
#define AUNITS 12288            // 16B units per A buffer (KC*256)

typedef float f32x4 __attribute__((ext_vector_type(4)));
typedef short bf16x8 __attribute__((ext_vector_type(8)));
typedef unsigned long long u64;

// A unit(row,kc,q) = kc*256 + (row>>4)*64 + q*16 + (row&15)
// Wf unit(blk,kc,q,r) = (blk*48+kc)*64 + q*16 + r, r = gate*4+j  (n-col)

__device__ __forceinline__ unsigned short f2bf(float f) {
  union { float f; uint32_t u; } v; v.f = f;
  return (unsigned short)((v.u + 0x7FFFu + ((v.u >> 16) & 1u)) >> 16);  // RNE
}
// nearest ODD-LSB bf16 (validity bit). trunc|1 IS the nearest odd value.
__device__ __forceinline__ unsigned short f2bf_odd(float f) {
  union { float f; uint32_t u; } v; v.f = f;
  return (unsigned short)((v.u >> 16) | 1u);
}
__device__ __forceinline__ float fsig(float x) {
  return __builtin_amdgcn_rcpf(1.0f + __expf(-x));
}
__device__ __forceinline__ float ftanh(float x) {
  return 2.0f * fsig(2.0f * x) - 1.0f;
}

__global__ __launch_bounds__(1024) void wf_kernel(
    const float* __restrict__ Wih, const float* __restrict__ Whh,
    unsigned short* __restrict__ Wf)
{
  __shared__ float tile[32][33];
  const int j0 = blockIdx.x * 32;           // gate-col tile
  const int k0 = blockIdx.y * 32;           // k tile
  const int tx = threadIdx.x & 31, ty = threadIdx.x >> 5;
  const int k = k0 + ty;
  tile[ty][tx] = (k < Hsz) ? Whh[(size_t)k * G4 + (j0 + tx)]
                           : Wih[(size_t)(k - Hsz) * G4 + (j0 + tx)];
  __syncthreads();
  if (threadIdx.x < 128) {
    const int gl = threadIdx.x & 31;        // local gate col in tile
    const int q8 = threadIdx.x >> 5;        // k-octet within kc
    const int g  = j0 + gl;                 // global gate col
    const int blk  = (g & 1023) >> 2;
    const int gate = g >> 10;
    const int r    = gate * 4 + (g & 3);    // n-col within block tile
    const int kc   = k0 >> 5;
    unsigned short pack[8];
    #pragma unroll
    for (int jj = 0; jj < 8; ++jj) pack[jj] = f2bf(tile[q8 * 8 + jj][gl]);
    const size_t unit = (size_t)((blk * KC + kc) * 64 + q8 * 16 + r);
    *(bf16x8*)(Wf + unit * 8) = *(bf16x8*)pack;
  }
}

// Per A[t]: clear h region to even/invalid (t=0: odd-LSB "zero" h) and
// write the emb region. Clearing every run kills cross-run stale-valid data.
__global__ __launch_bounds__(256) void init_kernel(
    const int* __restrict__ seq, const float* __restrict__ emb,
    unsigned short* __restrict__ Abufs, int* __restrict__ bar)
{
  const int t = blockIdx.x, tid = threadIdx.x;
  unsigned short* At = Abufs + (size_t)t * AUNITS * 8;
  {  // h region = units [0, 8192) = kc 0..31
    uint4 z;
    const uint32_t zv = (t == 0) ? 0x00010001u : 0u;
    z.x = z.y = z.z = z.w = zv;
    for (int i = tid; i < 8192; i += 256) ((uint4*)At)[i] = z;
  }
  const int c = 2 * tid;                    // emb col pair
  const int kc = 32 + (c >> 5), q = (c >> 3) & 3, j = c & 7;
  for (int row = 0; row < Bsz; ++row) {
    const int token = seq[row * Ssz + t];
    float2 e = ((const float2*)(emb + (size_t)token * Esz))[tid];
    uint32_t pe = (uint32_t)f2bf(e.x) | ((uint32_t)f2bf(e.y) << 16);
    const size_t unit = (size_t)(kc * 256 + (row >> 4) * 64 + q * 16 + (row & 15));
    *(uint32_t*)(At + unit * 8 + j) = pe;
  }
  if (t == 0) {
    for (int i = tid; i < 1024; i += 256) bar[i] = 0;
  }
}

__global__ __launch_bounds__(256, 1) void lstm_kernel(
    const float* __restrict__ bias, const unsigned short* __restrict__ Wf,
    unsigned short* __restrict__ Abufs,
    int* __restrict__ bar, float* __restrict__ out)
{
  (void)bar;
  const int blk  = blockIdx.x;          // owns h-cols [blk*4, blk*4+4)
  const int tid  = threadIdx.x;
  const int lane = tid & 63;
  const int w    = tid >> 6;            // wave = M-tile rows [w*16, w*16+16)
  const int l15  = lane & 15, quad = lane >> 4;

  __shared__ uint4 Wl[KC * 64];                 // 48 KB, resident all steps
  __shared__ unsigned short Hs[4][16][4];       // 512 B per-wave h transpose

  {  // one-time: W slice -> LDS
    const uint4* wfb = (const uint4*)Wf + (size_t)blk * (KC * 64);
    for (int i = tid; i < KC * 64; i += 256) Wl[i] = wfb[i];
  }

  // cell ownership: lanes l15<4 own (rows w*16+quad*4+r, col blk*4+l15)
  const bool owner = (l15 < 4);
  const int  bj = blk * 4 + (l15 & 3);
  const float bi  = bias[bj],        bf_ = bias[Hsz + bj];
  const float bg_ = bias[2*Hsz + bj], bo  = bias[3*Hsz + bj];
  float creg[4] = {0.f, 0.f, 0.f, 0.f};

  // h-store addressing: this block's cols live at (hkc, hq, hj0)
  const int hkc = blk >> 3, hq = (blk >> 1) & 3, hj0 = (blk & 1) * 4;

  __syncthreads();                      // Wl staged (only block barrier)

  // ---- emb prefetch (1 step ahead) ----
  uint4 eA[16];
  {
    const uint4* E0 = (const uint4*)Abufs;
    #pragma unroll
    for (int i = 0; i < 16; ++i) eA[i] = E0[(32 + i) * 256 + w * 64 + lane];
  }

  const u64 M = 0x0001000100010001ull;

  for (int t = 0; t < Ssz; ++t) {
    // ---- emb MFMAs (register-only), shadow work between store and sweep
    f32x4 accE = {0.f, 0.f, 0.f, 0.f};
    #pragma unroll
    for (int i = 0; i < 16; ++i)
      accE = __builtin_amdgcn_mfma_f32_16x16x32_bf16(
          __builtin_bit_cast(bf16x8, eA[i]),
          __builtin_bit_cast(bf16x8, Wl[(32 + i) * 64 + lane]), accE, 0, 0, 0);

    asm volatile("" ::: "memory");

    // ---- h sweep 1: 32 cached concurrent loads (XCD-L2 dedup) ----
    const uint4* Ac = (const uint4*)(Abufs + (size_t)t * AUNITS * 8);
    uint4 abuf[32];
    #pragma unroll
    for (int kc = 0; kc < 32; ++kc) abuf[kc] = Ac[kc * 256 + w * 64 + lane];

    __builtin_amdgcn_sched_barrier(0);

    uint32_t bad = 0;
    #pragma unroll
    for (int kc = 0; kc < 32; ++kc) {
      u64 lo = ((u64)abuf[kc].y << 32) | abuf[kc].x;
      u64 hi = ((u64)abuf[kc].w << 32) | abuf[kc].z;
      if (((lo & M) != M) || ((hi & M) != M)) bad |= (1u << kc);
    }

    // ---- retry sweeps: issue-pass (agent/MALL-direct, bad units only,
    //      all in flight) then check-pass. ~1 RT per sweep. ----
    while (__any((int)(bad != 0u))) {
      __builtin_amdgcn_s_sleep(8);
      #pragma unroll
      for (int kc = 0; kc < 32; ++kc) {
        if (bad & (1u << kc)) {
          const u64* base = (const u64*)Ac + (size_t)(kc * 256 + w * 64 + lane) * 2;
          u64 lo = __hip_atomic_load(base,     __ATOMIC_RELAXED, __HIP_MEMORY_SCOPE_AGENT);
          u64 hi = __hip_atomic_load(base + 1, __ATOMIC_RELAXED, __HIP_MEMORY_SCOPE_AGENT);
          abuf[kc].x = (uint32_t)lo; abuf[kc].y = (uint32_t)(lo >> 32);
          abuf[kc].z = (uint32_t)hi; abuf[kc].w = (uint32_t)(hi >> 32);
        }
      }
      __builtin_amdgcn_sched_barrier(0);
      uint32_t nbad = 0;
      #pragma unroll
      for (int kc = 0; kc < 32; ++kc) {
        if (bad & (1u << kc)) {
          u64 lo = ((u64)abuf[kc].y << 32) | abuf[kc].x;
          u64 hi = ((u64)abuf[kc].w << 32) | abuf[kc].z;
          if (((lo & M) != M) || ((hi & M) != M)) nbad |= (1u << kc);
        }
      }
      bad = nbad;
    }

    // ---- h-GEMM: 32 MFMAs, 4 accumulation chains ----
    f32x4 acc0 = {0.f, 0.f, 0.f, 0.f};
    f32x4 acc1 = {0.f, 0.f, 0.f, 0.f};
    f32x4 acc2 = {0.f, 0.f, 0.f, 0.f};
    f32x4 acc3 = {0.f, 0.f, 0.f, 0.f};
    #pragma unroll
    for (int kc = 0; kc < 32; ++kc) {
      const bf16x8 av = __builtin_bit_cast(bf16x8, abuf[kc]);
      const bf16x8 bv = __builtin_bit_cast(bf16x8, Wl[kc * 64 + lane]);
      if      ((kc & 3) == 0) acc0 = __builtin_amdgcn_mfma_f32_16x16x32_bf16(av, bv, acc0, 0, 0, 0);
      else if ((kc & 3) == 1) acc1 = __builtin_amdgcn_mfma_f32_16x16x32_bf16(av, bv, acc1, 0, 0, 0);
      else if ((kc & 3) == 2) acc2 = __builtin_amdgcn_mfma_f32_16x16x32_bf16(av, bv, acc2, 0, 0, 0);
      else                    acc3 = __builtin_amdgcn_mfma_f32_16x16x32_bf16(av, bv, acc3, 0, 0, 0);
    }
    f32x4 acc;
    acc.x = accE.x + (acc0.x + acc1.x) + (acc2.x + acc3.x);
    acc.y = accE.y + (acc0.y + acc1.y) + (acc2.y + acc3.y);
    acc.z = accE.z + (acc0.z + acc1.z) + (acc2.z + acc3.z);
    acc.w = accE.w + (acc0.w + acc1.w) + (acc2.w + acc3.w);

    // ---- in-wave LSTM cell (acc[r]: gate l15>>2, col l15&3, row +quad*4+r)
    float hv[4];
    #pragma unroll
    for (int r = 0; r < 4; ++r) {
      float gf = __shfl_xor(acc[r], 4);
      float gg = __shfl_xor(acc[r], 8);
      float go = __shfl_xor(acc[r], 12);
      float c  = fsig(gf + bf_) * creg[r]
               + fsig(acc[r] + bi) * ftanh(gg + bg_);
      float h  = fsig(go + bo) * ftanh(c);
      if (owner) { creg[r] = c; hv[r] = h; }
    }

    if (t == Ssz - 1) {
      if (owner) {
        #pragma unroll
        for (int r = 0; r < 4; ++r) {
          const int row = w * 16 + quad * 4 + r;
          out[(size_t)row * Hsz + bj] = hv[r];
          out[(size_t)(Bsz * Hsz) + (size_t)row * Hsz + bj] = creg[r];
        }
      }
      return;
    }

    // ---- fire-and-forget: per-wave LDS transpose -> 8B odd-LSB u64 store
    if (owner) {
      #pragma unroll
      for (int r = 0; r < 4; ++r) Hs[w][quad * 4 + r][l15] = f2bf_odd(hv[r]);
    }
    unsigned short* An = Abufs + (size_t)(t + 1) * AUNITS * 8;
    if (lane < 16) {
      u64 hp = *(const u64*)&Hs[w][lane][0];
      const size_t unit = (size_t)(hkc * 256 + w * 64 + hq * 16 + lane);
      __hip_atomic_store((u64*)(An + unit * 8 + hj0), hp,
                         __ATOMIC_RELAXED, __HIP_MEMORY_SCOPE_AGENT);
    }
    asm volatile("" ::: "memory");

    // ---- refill emb prefetch for t+1 (init-written, always valid) ----
    const uint4* An4 = (const uint4*)An;
    #pragma unroll
    for (int i = 0; i < 16; ++i) eA[i] = An4[(32 + i) * 256 + w * 64 + lane];
  }
}

extern "C" void kernel_launch(void* const* d_in, const int* in_sizes, int n_in,
                              void* d_out, int out_size, void* d_ws, size_t ws_size,
                              hipStream_t stream) {
  (void)in_sizes; (void)n_in; (void)out_size; (void)ws_size;
  const int*   seq  = (const int*)d_in[0];     // [64][512] int32
  const float* emb  = (const float*)d_in[1];   // [32000][512] fp32
  const float* Wih  = (const float*)d_in[2];   // [512][4096] fp32
  const float* Whh  = (const float*)d_in[3];   // [1024][4096] fp32
  const float* bias = (const float*)d_in[4];   // [4096] fp32
  float* out = (float*)d_out;                  // h[64][1024] then c[64][1024]

  unsigned short* Wf    = (unsigned short*)d_ws;              // 12.58 MB
  unsigned short* Abufs = Wf + (size_t)NBLK * KC * 64 * 8;    // 512*192KB
  int* bar = (int*)(Abufs + (size_t)Ssz * AUNITS * 8);        // unused pad

  wf_kernel<<<dim3(G4 / 32, Ksz / 32), 1024, 0, stream>>>(Wih, Whh, Wf);
  init_kernel<<<Ssz, 256, 0, stream>>>(seq, emb, Abufs, bar);
  lstm_kernel<<<NBLK, 256, 0, stream>>>(bias, Wf, Abufs, bar, out);
}

// Round 4
// 2511.707 us; speedup vs baseline: 4.4107x; 1.4540x over previous
//
#include <hip/hip_runtime.h>
#include <stdint.h>

// LSTM encoder: B=64, S=512, V=32000, E=512, H=1024. Returns final (h, c) fp32.
//
// Round-13: sentinel data-poll (narrow) + single cached sweep + batched
// recovery. r12 post-mortem: data-driven sync was right, but polling with
// the FULL 32-unit sweep (32KB/wave/iter, vmcnt(0) over not-yet-written
// lines, ~4MB/iter global at MALL) made detection granularity ~1.5us and
// congested the fabric -> 7.1us/step, worse than r9's flags (4.8).
// Fix: poll must be narrow, data fetched once.
//  - Each lane agent-polls ONLY its own kc=0 unit (16B; producers are
//    blocks 0..7, one per XCD -- representative lockstep sample, and the
//    polled bytes ARE the kc=0 operand). Tight 2-load loop, ~1KB/wave/iter.
//  - On sentinel-valid: cached sweep of kc=1..31 ONCE (XCD-L2 dedup across
//    the 32 blocks/XCD), LSB-validate, then r12's batched issue/check
//    retry (concurrent agent reloads, exec-masked to bad units, s_sleep(2))
//    -- ~1 RT per recovery round regardless of laggard count.
//  - Every wave paces itself on its own rows: NO flags, NO block barrier
//    in the loop, no clock.
//  - Ground truth unchanged (r11/r12-proven): LSB-odd validity, per-run
//    init clear of all h regions, agent-scope recovery; deadlock-free
//    (step-t wait depends only on step t-1 fire-and-forget stores).
//  - emb MFMAs + eA prefetch in the shadow; h-MFMA in 4 chains.

#define Bsz 64
#define Ssz 512
#define Esz 512
#define Hsz 1024
#define G4  4096
#define Ksz 1536
#define KC  48      // Ksz/32
#define NBLK 256
#define AUNITS 12288            // 16B units per A buffer (KC*256)

typedef float f32x4 __attribute__((ext_vector_type(4)));
typedef short bf16x8 __attribute__((ext_vector_type(8)));
typedef unsigned long long u64;

// A unit(row,kc,q) = kc*256 + (row>>4)*64 + q*16 + (row&15)
// Wf unit(blk,kc,q,r) = (blk*48+kc)*64 + q*16 + r, r = gate*4+j  (n-col)

__device__ __forceinline__ unsigned short f2bf(float f) {
  union { float f; uint32_t u; } v; v.f = f;
  return (unsigned short)((v.u + 0x7FFFu + ((v.u >> 16) & 1u)) >> 16);  // RNE
}
// nearest ODD-LSB bf16 (validity bit). trunc|1 IS the nearest odd value.
__device__ __forceinline__ unsigned short f2bf_odd(float f) {
  union { float f; uint32_t u; } v; v.f = f;
  return (unsigned short)((v.u >> 16) | 1u);
}
__device__ __forceinline__ float fsig(float x) {
  return __builtin_amdgcn_rcpf(1.0f + __expf(-x));
}
__device__ __forceinline__ float ftanh(float x) {
  return 2.0f * fsig(2.0f * x) - 1.0f;
}

__global__ __launch_bounds__(1024) void wf_kernel(
    const float* __restrict__ Wih, const float* __restrict__ Whh,
    unsigned short* __restrict__ Wf)
{
  __shared__ float tile[32][33];
  const int j0 = blockIdx.x * 32;           // gate-col tile
  const int k0 = blockIdx.y * 32;           // k tile
  const int tx = threadIdx.x & 31, ty = threadIdx.x >> 5;
  const int k = k0 + ty;
  tile[ty][tx] = (k < Hsz) ? Whh[(size_t)k * G4 + (j0 + tx)]
                           : Wih[(size_t)(k - Hsz) * G4 + (j0 + tx)];
  __syncthreads();
  if (threadIdx.x < 128) {
    const int gl = threadIdx.x & 31;        // local gate col in tile
    const int q8 = threadIdx.x >> 5;        // k-octet within kc
    const int g  = j0 + gl;                 // global gate col
    const int blk  = (g & 1023) >> 2;
    const int gate = g >> 10;
    const int r    = gate * 4 + (g & 3);    // n-col within block tile
    const int kc   = k0 >> 5;
    unsigned short pack[8];
    #pragma unroll
    for (int jj = 0; jj < 8; ++jj) pack[jj] = f2bf(tile[q8 * 8 + jj][gl]);
    const size_t unit = (size_t)((blk * KC + kc) * 64 + q8 * 16 + r);
    *(bf16x8*)(Wf + unit * 8) = *(bf16x8*)pack;
  }
}

// Per A[t]: clear h region to even/invalid (t=0: odd-LSB "zero" h) and
// write the emb region. Clearing every run kills cross-run stale-valid data.
__global__ __launch_bounds__(256) void init_kernel(
    const int* __restrict__ seq, const float* __restrict__ emb,
    unsigned short* __restrict__ Abufs, int* __restrict__ bar)
{
  const int t = blockIdx.x, tid = threadIdx.x;
  unsigned short* At = Abufs + (size_t)t * AUNITS * 8;
  {  // h region = units [0, 8192) = kc 0..31
    uint4 z;
    const uint32_t zv = (t == 0) ? 0x00010001u : 0u;
    z.x = z.y = z.z = z.w = zv;
    for (int i = tid; i < 8192; i += 256) ((uint4*)At)[i] = z;
  }
  const int c = 2 * tid;                    // emb col pair
  const int kc = 32 + (c >> 5), q = (c >> 3) & 3, j = c & 7;
  for (int row = 0; row < Bsz; ++row) {
    const int token = seq[row * Ssz + t];
    float2 e = ((const float2*)(emb + (size_t)token * Esz))[tid];
    uint32_t pe = (uint32_t)f2bf(e.x) | ((uint32_t)f2bf(e.y) << 16);
    const size_t unit = (size_t)(kc * 256 + (row >> 4) * 64 + q * 16 + (row & 15));
    *(uint32_t*)(At + unit * 8 + j) = pe;
  }
  if (t == 0) {
    for (int i = tid; i < 1024; i += 256) bar[i] = 0;
  }
}

__global__ __launch_bounds__(256, 1) void lstm_kernel(
    const float* __restrict__ bias, const unsigned short* __restrict__ Wf,
    unsigned short* __restrict__ Abufs,
    int* __restrict__ bar, float* __restrict__ out)
{
  (void)bar;
  const int blk  = blockIdx.x;          // owns h-cols [blk*4, blk*4+4)
  const int tid  = threadIdx.x;
  const int lane = tid & 63;
  const int w    = tid >> 6;            // wave = M-tile rows [w*16, w*16+16)
  const int l15  = lane & 15, quad = lane >> 4;

  __shared__ uint4 Wl[KC * 64];                 // 48 KB, resident all steps
  __shared__ unsigned short Hs[4][16][4];       // 512 B per-wave h transpose

  {  // one-time: W slice -> LDS
    const uint4* wfb = (const uint4*)Wf + (size_t)blk * (KC * 64);
    for (int i = tid; i < KC * 64; i += 256) Wl[i] = wfb[i];
  }

  // cell ownership: lanes l15<4 own (rows w*16+quad*4+r, col blk*4+l15)
  const bool owner = (l15 < 4);
  const int  bj = blk * 4 + (l15 & 3);
  const float bi  = bias[bj],        bf_ = bias[Hsz + bj];
  const float bg_ = bias[2*Hsz + bj], bo  = bias[3*Hsz + bj];
  float creg[4] = {0.f, 0.f, 0.f, 0.f};

  // h-store addressing: this block's cols live at (hkc, hq, hj0)
  const int hkc = blk >> 3, hq = (blk >> 1) & 3, hj0 = (blk & 1) * 4;

  __syncthreads();                      // Wl staged (only block barrier)

  // ---- emb prefetch (1 step ahead) ----
  uint4 eA[16];
  {
    const uint4* E0 = (const uint4*)Abufs;
    #pragma unroll
    for (int i = 0; i < 16; ++i) eA[i] = E0[(32 + i) * 256 + w * 64 + lane];
  }

  const u64 M = 0x0001000100010001ull;

  for (int t = 0; t < Ssz; ++t) {
    // ---- emb MFMAs (register-only), shadow work ----
    f32x4 accE = {0.f, 0.f, 0.f, 0.f};
    #pragma unroll
    for (int i = 0; i < 16; ++i)
      accE = __builtin_amdgcn_mfma_f32_16x16x32_bf16(
          __builtin_bit_cast(bf16x8, eA[i]),
          __builtin_bit_cast(bf16x8, Wl[(32 + i) * 64 + lane]), accE, 0, 0, 0);

    asm volatile("" ::: "memory");

    const uint4* Ac = (const uint4*)(Abufs + (size_t)t * AUNITS * 8);
    uint4 abuf[32];

    // ---- sentinel: tight agent-poll of own kc=0 unit (16B, 2 loads) ----
    {
      const u64* s0 = (const u64*)Ac + (size_t)(w * 64 + lane) * 2;
      u64 lo0, hi0;
      for (;;) {
        lo0 = __hip_atomic_load(s0,     __ATOMIC_RELAXED, __HIP_MEMORY_SCOPE_AGENT);
        hi0 = __hip_atomic_load(s0 + 1, __ATOMIC_RELAXED, __HIP_MEMORY_SCOPE_AGENT);
        const bool ok = (((lo0 & M) == M) && ((hi0 & M) == M));
        if (__all(ok)) break;
        __builtin_amdgcn_s_sleep(1);
      }
      abuf[0].x = (uint32_t)lo0; abuf[0].y = (uint32_t)(lo0 >> 32);
      abuf[0].z = (uint32_t)hi0; abuf[0].w = (uint32_t)(hi0 >> 32);
    }

    // ---- single cached sweep kc=1..31 (XCD-L2 dedup across blocks) ----
    #pragma unroll
    for (int kc = 1; kc < 32; ++kc) abuf[kc] = Ac[kc * 256 + w * 64 + lane];

    __builtin_amdgcn_sched_barrier(0);

    uint32_t bad = 0;
    #pragma unroll
    for (int kc = 1; kc < 32; ++kc) {
      u64 lo = ((u64)abuf[kc].y << 32) | abuf[kc].x;
      u64 hi = ((u64)abuf[kc].w << 32) | abuf[kc].z;
      if (((lo & M) != M) || ((hi & M) != M)) bad |= (1u << kc);
    }

    // ---- batched recovery: issue-pass (concurrent agent reloads of bad
    //      units only) then check-pass; ~1 RT per round ----
    while (__any((int)(bad != 0u))) {
      __builtin_amdgcn_s_sleep(2);
      #pragma unroll
      for (int kc = 1; kc < 32; ++kc) {
        if (bad & (1u << kc)) {
          const u64* base = (const u64*)Ac + (size_t)(kc * 256 + w * 64 + lane) * 2;
          u64 lo = __hip_atomic_load(base,     __ATOMIC_RELAXED, __HIP_MEMORY_SCOPE_AGENT);
          u64 hi = __hip_atomic_load(base + 1, __ATOMIC_RELAXED, __HIP_MEMORY_SCOPE_AGENT);
          abuf[kc].x = (uint32_t)lo; abuf[kc].y = (uint32_t)(lo >> 32);
          abuf[kc].z = (uint32_t)hi; abuf[kc].w = (uint32_t)(hi >> 32);
        }
      }
      __builtin_amdgcn_sched_barrier(0);
      uint32_t nbad = 0;
      #pragma unroll
      for (int kc = 1; kc < 32; ++kc) {
        if (bad & (1u << kc)) {
          u64 lo = ((u64)abuf[kc].y << 32) | abuf[kc].x;
          u64 hi = ((u64)abuf[kc].w << 32) | abuf[kc].z;
          if (((lo & M) != M) || ((hi & M) != M)) nbad |= (1u << kc);
        }
      }
      bad = nbad;
    }

    // ---- h-GEMM: 32 MFMAs, 4 accumulation chains ----
    f32x4 acc0 = {0.f, 0.f, 0.f, 0.f};
    f32x4 acc1 = {0.f, 0.f, 0.f, 0.f};
    f32x4 acc2 = {0.f, 0.f, 0.f, 0.f};
    f32x4 acc3 = {0.f, 0.f, 0.f, 0.f};
    #pragma unroll
    for (int kc = 0; kc < 32; ++kc) {
      const bf16x8 av = __builtin_bit_cast(bf16x8, abuf[kc]);
      const bf16x8 bv = __builtin_bit_cast(bf16x8, Wl[kc * 64 + lane]);
      if      ((kc & 3) == 0) acc0 = __builtin_amdgcn_mfma_f32_16x16x32_bf16(av, bv, acc0, 0, 0, 0);
      else if ((kc & 3) == 1) acc1 = __builtin_amdgcn_mfma_f32_16x16x32_bf16(av, bv, acc1, 0, 0, 0);
      else if ((kc & 3) == 2) acc2 = __builtin_amdgcn_mfma_f32_16x16x32_bf16(av, bv, acc2, 0, 0, 0);
      else                    acc3 = __builtin_amdgcn_mfma_f32_16x16x32_bf16(av, bv, acc3, 0, 0, 0);
    }
    f32x4 acc;
    acc.x = accE.x + (acc0.x + acc1.x) + (acc2.x + acc3.x);
    acc.y = accE.y + (acc0.y + acc1.y) + (acc2.y + acc3.y);
    acc.z = accE.z + (acc0.z + acc1.z) + (acc2.z + acc3.z);
    acc.w = accE.w + (acc0.w + acc1.w) + (acc2.w + acc3.w);

    // ---- in-wave LSTM cell (acc[r]: gate l15>>2, col l15&3, row +quad*4+r)
    float hv[4];
    #pragma unroll
    for (int r = 0; r < 4; ++r) {
      float gf = __shfl_xor(acc[r], 4);
      float gg = __shfl_xor(acc[r], 8);
      float go = __shfl_xor(acc[r], 12);
      float c  = fsig(gf + bf_) * creg[r]
               + fsig(acc[r] + bi) * ftanh(gg + bg_);
      float h  = fsig(go + bo) * ftanh(c);
      if (owner) { creg[r] = c; hv[r] = h; }
    }

    if (t == Ssz - 1) {
      if (owner) {
        #pragma unroll
        for (int r = 0; r < 4; ++r) {
          const int row = w * 16 + quad * 4 + r;
          out[(size_t)row * Hsz + bj] = hv[r];
          out[(size_t)(Bsz * Hsz) + (size_t)row * Hsz + bj] = creg[r];
        }
      }
      return;
    }

    // ---- fire-and-forget: per-wave LDS transpose -> 8B odd-LSB u64 store
    if (owner) {
      #pragma unroll
      for (int r = 0; r < 4; ++r) Hs[w][quad * 4 + r][l15] = f2bf_odd(hv[r]);
    }
    unsigned short* An = Abufs + (size_t)(t + 1) * AUNITS * 8;
    if (lane < 16) {
      u64 hp = *(const u64*)&Hs[w][lane][0];
      const size_t unit = (size_t)(hkc * 256 + w * 64 + hq * 16 + lane);
      __hip_atomic_store((u64*)(An + unit * 8 + hj0), hp,
                         __ATOMIC_RELAXED, __HIP_MEMORY_SCOPE_AGENT);
    }
    asm volatile("" ::: "memory");

    // ---- refill emb prefetch for t+1 (init-written, always valid) ----
    const uint4* An4 = (const uint4*)An;
    #pragma unroll
    for (int i = 0; i < 16; ++i) eA[i] = An4[(32 + i) * 256 + w * 64 + lane];
  }
}

extern "C" void kernel_launch(void* const* d_in, const int* in_sizes, int n_in,
                              void* d_out, int out_size, void* d_ws, size_t ws_size,
                              hipStream_t stream) {
  (void)in_sizes; (void)n_in; (void)out_size; (void)ws_size;
  const int*   seq  = (const int*)d_in[0];     // [64][512] int32
  const float* emb  = (const float*)d_in[1];   // [32000][512] fp32
  const float* Wih  = (const float*)d_in[2];   // [512][4096] fp32
  const float* Whh  = (const float*)d_in[3];   // [1024][4096] fp32
  const float* bias = (const float*)d_in[4];   // [4096] fp32
  float* out = (float*)d_out;                  // h[64][1024] then c[64][1024]

  unsigned short* Wf    = (unsigned short*)d_ws;              // 12.58 MB
  unsigned short* Abufs = Wf + (size_t)NBLK * KC * 64 * 8;    // 512*192KB
  int* bar = (int*)(Abufs + (size_t)Ssz * AUNITS * 8);        // unused pad

  wf_kernel<<<dim3(G4 / 32, Ksz / 32), 1024, 0, stream>>>(Wih, Whh, Wf);
  init_kernel<<<Ssz, 256, 0, stream>>>(seq, emb, Abufs, bar);
  lstm_kernel<<<NBLK, 256, 0, stream>>>(bias, Wf, Abufs, bar, out);
}